// Round 3
// baseline (752.517 us; speedup 1.0000x reference)
//
#include <hip/hip_runtime.h>

#define HDIM 64

__device__ __forceinline__ float fast_sigmoid(float v) {
    return __builtin_amdgcn_rcpf(1.0f + __builtin_amdgcn_exp2f(-1.442695041f * v));
}

__device__ __forceinline__ float fast_tanh(float v) {
    return 1.0f - 2.0f * __builtin_amdgcn_rcpf(1.0f + __builtin_amdgcn_exp2f(2.885390082f * v));
}

// 256 threads = 4 waves per batch element.
// lane l (0..63) of wave w owns gate-row r = j*64 + m, where
//   j = l>>4  (gate: 0=i,1=f,2=g,3=o),  m = w*16 + (l&15)  (output index).
// The row's 64 recurrent weights are PINNED into VGPRs via empty asm.
__global__ __launch_bounds__(256, 2)
void bilstm_kernel(const float* __restrict__ x,
                   const float* __restrict__ w_ih_f,
                   const float* __restrict__ w_hh_f,
                   const float* __restrict__ b_ih_f,
                   const float* __restrict__ b_hh_f,
                   const float* __restrict__ w_ih_b,
                   const float* __restrict__ b_ih_b,
                   const float* __restrict__ b_hh_b,
                   const float* __restrict__ w_fc,
                   const float* __restrict__ b_fc,
                   float* __restrict__ out,
                   int T)
{
    const int b   = blockIdx.x;
    const int tid = threadIdx.x;
    const int w   = tid >> 6;              // wave 0..3
    const int l   = tid & 63;              // lane 0..63
    const int j   = l >> 4;                // gate id
    const int m   = (w << 4) | (l & 15);   // output index 0..63
    const int r   = (j << 6) | m;          // row in [0,256)

    __shared__ float hbuf[2][HDIM];

    // ---- per-lane weights into registers (pinned) ----
    float wreg[HDIM];
    {
        const float* row = w_hh_f + (size_t)r * HDIM;
        #pragma unroll
        for (int q = 0; q < 16; ++q) {
            float4 v = *(const float4*)(row + 4 * q);
            wreg[4 * q + 0] = v.x;
            wreg[4 * q + 1] = v.y;
            wreg[4 * q + 2] = v.z;
            wreg[4 * q + 3] = v.w;
        }
    }
    // Pin: forbid rematerialization of the weight loads inside the t-loop.
    #pragma unroll
    for (int q = 0; q < 8; ++q) {
        asm volatile("" : "+v"(wreg[8*q+0]), "+v"(wreg[8*q+1]),
                          "+v"(wreg[8*q+2]), "+v"(wreg[8*q+3]),
                          "+v"(wreg[8*q+4]), "+v"(wreg[8*q+5]),
                          "+v"(wreg[8*q+6]), "+v"(wreg[8*q+7]));
    }

    float4 wx = *(const float4*)(w_ih_f + (size_t)r * 4);
    asm volatile("" : "+v"(wx.x), "+v"(wx.y), "+v"(wx.z), "+v"(wx.w));
    const float bz = b_ih_f[r] + b_hh_f[r];

    if (tid < HDIM) hbuf[0][tid] = 0.0f;
    __syncthreads();

    const float* xb = x + (size_t)b * T * 4;
    float4 xcur = *(const float4*)(xb);    // t = 0
    float c = 0.0f, h = 0.0f;
    int rb = 0;

    for (int t = 0; t < T; ++t) {
        const int tn = (t + 1 < T) ? t + 1 : T - 1;
        float4 xnext = *(const float4*)(xb + 4 * tn);

        // 4 independent accumulator chains
        float a0 = bz, a1 = 0.0f, a2 = 0.0f, a3 = 0.0f;
        const float4* hp = (const float4*)hbuf[rb];
        #pragma unroll
        for (int q = 0; q < 16; ++q) {
            float4 hq = hp[q];             // broadcast read (same addr all lanes)
            a0 += wreg[4 * q + 0] * hq.x;
            a1 += wreg[4 * q + 1] * hq.y;
            a2 += wreg[4 * q + 2] * hq.z;
            a3 += wreg[4 * q + 3] * hq.w;
        }
        a0 += wx.x * xcur.x + wx.z * xcur.z;
        a1 += wx.y * xcur.y + wx.w * xcur.w;
        float a = (a0 + a1) + (a2 + a3);

        // activation: sigmoid for j=0,1,3 ; tanh for j=2
        const float s = (j == 2) ? 2.885390082f : -1.442695041f;
        const float e = __builtin_amdgcn_exp2f(s * a);
        const float rr = __builtin_amdgcn_rcpf(1.0f + e);
        const float gv = (j == 2) ? 1.0f - 2.0f * rr : rr;

        // gather the 4 gate values of output m (lanes l, l^16, l^32, l^48)
        const float v1 = __shfl_xor(gv, 16);
        const float pe = ((j & 1) == 0) ? gv : v1;   // i (j<2) or g (j>=2)
        const float po = ((j & 1) == 0) ? v1 : gv;   // f (j<2) or o (j>=2)
        const float qe = __shfl_xor(pe, 32);
        const float qo = __shfl_xor(po, 32);
        const float gi = (j < 2) ? pe : qe;
        const float gf = (j < 2) ? po : qo;
        const float gg = (j < 2) ? qe : pe;
        const float go = (j < 2) ? qo : po;

        c = gf * c + gi * gg;
        h = go * fast_tanh(c);

        if (l < 16) hbuf[rb ^ 1][(w << 4) | l] = h;  // j==0 lanes write h[m]
        __syncthreads();
        rb ^= 1;
        xcur = xnext;
    }

    // ---- epilogue: wave 0 handles backward cell + fc + sigmoid ----
    if (w == 0) {
        // backward-direction single cell from zero state at x[:, T-1]
        float gb[4];
        #pragma unroll
        for (int jj = 0; jj < 4; ++jj) {
            const int rr2 = (jj << 6) | l;
            float4 wb = *(const float4*)(w_ih_b + (size_t)rr2 * 4);
            gb[jj] = b_ih_b[rr2] + b_hh_b[rr2]
                   + wb.x * xcur.x + wb.y * xcur.y + wb.z * xcur.z + wb.w * xcur.w;
        }
        const float ib  = fast_sigmoid(gb[0]);
        const float ggb = fast_tanh(gb[2]);
        const float ob  = fast_sigmoid(gb[3]);
        const float cb  = ib * ggb;
        const float hb  = ob * fast_tanh(cb);

        const float hf = hbuf[rb][l];
        float p = w_fc[l] * hf + w_fc[HDIM + l] * hb;
        #pragma unroll
        for (int off = 32; off; off >>= 1) p += __shfl_xor(p, off);

        if (l == 0) out[b] = fast_sigmoid(p + b_fc[0]);
    }
}

extern "C" void kernel_launch(void* const* d_in, const int* in_sizes, int n_in,
                              void* d_out, int out_size, void* d_ws, size_t ws_size,
                              hipStream_t stream) {
    const float* x      = (const float*)d_in[0];
    const float* w_ih_f = (const float*)d_in[1];
    const float* w_hh_f = (const float*)d_in[2];
    const float* b_ih_f = (const float*)d_in[3];
    const float* b_hh_f = (const float*)d_in[4];
    const float* w_ih_b = (const float*)d_in[5];
    // d_in[6] = w_hh_b — unused (backward cell starts from zero state)
    const float* b_ih_b = (const float*)d_in[7];
    const float* b_hh_b = (const float*)d_in[8];
    const float* w_fc   = (const float*)d_in[9];
    const float* b_fc   = (const float*)d_in[10];
    float* out = (float*)d_out;

    const int B = out_size;                 // 512
    const int T = in_sizes[0] / (B * 4);    // 1000

    bilstm_kernel<<<dim3(B), dim3(256), 0, stream>>>(
        x, w_ih_f, w_hh_f, b_ih_f, b_hh_f,
        w_ih_b, b_ih_b, b_hh_b, w_fc, b_fc, out, T);
}

// Round 4
// 690.961 us; speedup vs baseline: 1.0891x; 1.0891x over previous
//
#include <hip/hip_runtime.h>

#define HDIM 64

__device__ __forceinline__ float fast_sigmoid(float v) {
    return __builtin_amdgcn_rcpf(1.0f + __builtin_amdgcn_exp2f(-1.442695041f * v));
}

__device__ __forceinline__ float fast_tanh(float v) {
    return 1.0f - 2.0f * __builtin_amdgcn_rcpf(1.0f + __builtin_amdgcn_exp2f(2.885390082f * v));
}

// 256 threads = 4 waves per batch element.
// lane l (0..63) of wave w owns gate-row r = j*64 + m, where
//   j = l>>4  (gate: 0=i,1=f,2=g,3=o),  m = w*16 + (l&15)  (output index).
// amdgpu_waves_per_eu(2,2) fixes the regalloc budget at 256 VGPRs/wave so the
// 64 per-lane recurrent weights (pinned by empty asm) stay truly register-resident.
__global__ __launch_bounds__(256)
__attribute__((amdgpu_waves_per_eu(2, 2)))
void bilstm_kernel(const float* __restrict__ x,
                   const float* __restrict__ w_ih_f,
                   const float* __restrict__ w_hh_f,
                   const float* __restrict__ b_ih_f,
                   const float* __restrict__ b_hh_f,
                   const float* __restrict__ w_ih_b,
                   const float* __restrict__ b_ih_b,
                   const float* __restrict__ b_hh_b,
                   const float* __restrict__ w_fc,
                   const float* __restrict__ b_fc,
                   float* __restrict__ out,
                   int T)
{
    const int b   = blockIdx.x;
    const int tid = threadIdx.x;
    const int w   = tid >> 6;              // wave 0..3
    const int l   = tid & 63;              // lane 0..63
    const int j   = l >> 4;                // gate id
    const int m   = (w << 4) | (l & 15);   // output index 0..63
    const int r   = (j << 6) | m;          // row in [0,256)

    __shared__ float hbuf[2][HDIM];

    // ---- per-lane weights into registers (pinned) ----
    float wreg[HDIM];
    {
        const float* row = w_hh_f + (size_t)r * HDIM;
        #pragma unroll
        for (int q = 0; q < 16; ++q) {
            float4 v = *(const float4*)(row + 4 * q);
            wreg[4 * q + 0] = v.x;
            wreg[4 * q + 1] = v.y;
            wreg[4 * q + 2] = v.z;
            wreg[4 * q + 3] = v.w;
        }
    }
    // Pin: forbid rematerialization of the weight loads inside the t-loop.
    #pragma unroll
    for (int q = 0; q < 8; ++q) {
        asm volatile("" : "+v"(wreg[8*q+0]), "+v"(wreg[8*q+1]),
                          "+v"(wreg[8*q+2]), "+v"(wreg[8*q+3]),
                          "+v"(wreg[8*q+4]), "+v"(wreg[8*q+5]),
                          "+v"(wreg[8*q+6]), "+v"(wreg[8*q+7]));
    }

    float4 wx = *(const float4*)(w_ih_f + (size_t)r * 4);
    asm volatile("" : "+v"(wx.x), "+v"(wx.y), "+v"(wx.z), "+v"(wx.w));
    const float bz = b_ih_f[r] + b_hh_f[r];

    if (tid < HDIM) hbuf[0][tid] = 0.0f;
    __syncthreads();

    const float* xb = x + (size_t)b * T * 4;
    float4 xcur = *(const float4*)(xb);    // t = 0
    float c = 0.0f, h = 0.0f;
    int rb = 0;

    for (int t = 0; t < T; ++t) {
        const int tn = (t + 1 < T) ? t + 1 : T - 1;
        float4 xnext = *(const float4*)(xb + 4 * tn);

        // 4 independent accumulator chains
        float a0 = bz, a1 = 0.0f, a2 = 0.0f, a3 = 0.0f;
        const float4* hp = (const float4*)hbuf[rb];
        #pragma unroll
        for (int q = 0; q < 16; ++q) {
            float4 hq = hp[q];             // broadcast read (same addr all lanes)
            a0 += wreg[4 * q + 0] * hq.x;
            a1 += wreg[4 * q + 1] * hq.y;
            a2 += wreg[4 * q + 2] * hq.z;
            a3 += wreg[4 * q + 3] * hq.w;
        }
        a0 += wx.x * xcur.x + wx.z * xcur.z;
        a1 += wx.y * xcur.y + wx.w * xcur.w;
        float a = (a0 + a1) + (a2 + a3);

        // activation: sigmoid for j=0,1,3 ; tanh for j=2
        const float s = (j == 2) ? 2.885390082f : -1.442695041f;
        const float e = __builtin_amdgcn_exp2f(s * a);
        const float rr = __builtin_amdgcn_rcpf(1.0f + e);
        const float gv = (j == 2) ? 1.0f - 2.0f * rr : rr;

        // gather the 4 gate values of output m (lanes l, l^16, l^32, l^48)
        const float v1 = __shfl_xor(gv, 16);
        const float pe = ((j & 1) == 0) ? gv : v1;   // i (j<2) or g (j>=2)
        const float po = ((j & 1) == 0) ? v1 : gv;   // f (j<2) or o (j>=2)
        const float qe = __shfl_xor(pe, 32);
        const float qo = __shfl_xor(po, 32);
        const float gi = (j < 2) ? pe : qe;
        const float gf = (j < 2) ? po : qo;
        const float gg = (j < 2) ? qe : pe;
        const float go = (j < 2) ? qo : po;

        c = gf * c + gi * gg;
        h = go * fast_tanh(c);

        if (l < 16) hbuf[rb ^ 1][(w << 4) | l] = h;  // j==0 lanes write h[m]
        __syncthreads();
        rb ^= 1;
        xcur = xnext;
    }

    // ---- epilogue: wave 0 handles backward cell + fc + sigmoid ----
    if (w == 0) {
        // backward-direction single cell from zero state at x[:, T-1]
        float gb[4];
        #pragma unroll
        for (int jj = 0; jj < 4; ++jj) {
            const int rr2 = (jj << 6) | l;
            float4 wb = *(const float4*)(w_ih_b + (size_t)rr2 * 4);
            gb[jj] = b_ih_b[rr2] + b_hh_b[rr2]
                   + wb.x * xcur.x + wb.y * xcur.y + wb.z * xcur.z + wb.w * xcur.w;
        }
        const float ib  = fast_sigmoid(gb[0]);
        const float ggb = fast_tanh(gb[2]);
        const float ob  = fast_sigmoid(gb[3]);
        const float cb  = ib * ggb;
        const float hb  = ob * fast_tanh(cb);

        const float hf = hbuf[rb][l];
        float p = w_fc[l] * hf + w_fc[HDIM + l] * hb;
        #pragma unroll
        for (int off = 32; off; off >>= 1) p += __shfl_xor(p, off);

        if (l == 0) out[b] = fast_sigmoid(p + b_fc[0]);
    }
}

extern "C" void kernel_launch(void* const* d_in, const int* in_sizes, int n_in,
                              void* d_out, int out_size, void* d_ws, size_t ws_size,
                              hipStream_t stream) {
    const float* x      = (const float*)d_in[0];
    const float* w_ih_f = (const float*)d_in[1];
    const float* w_hh_f = (const float*)d_in[2];
    const float* b_ih_f = (const float*)d_in[3];
    const float* b_hh_f = (const float*)d_in[4];
    const float* w_ih_b = (const float*)d_in[5];
    // d_in[6] = w_hh_b — unused (backward cell starts from zero state)
    const float* b_ih_b = (const float*)d_in[7];
    const float* b_hh_b = (const float*)d_in[8];
    const float* w_fc   = (const float*)d_in[9];
    const float* b_fc   = (const float*)d_in[10];
    float* out = (float*)d_out;

    const int B = out_size;                 // 512
    const int T = in_sizes[0] / (B * 4);    // 1000

    bilstm_kernel<<<dim3(B), dim3(256), 0, stream>>>(
        x, w_ih_f, w_hh_f, b_ih_f, b_hh_f,
        w_ih_b, b_ih_b, b_hh_b, w_fc, b_fc, out, T);
}

// Round 5
// 535.686 us; speedup vs baseline: 1.4048x; 1.2899x over previous
//
#include <hip/hip_runtime.h>

#define HDIM 64

__device__ __forceinline__ float fast_sigmoid(float v) {
    return __builtin_amdgcn_rcpf(1.0f + __builtin_amdgcn_exp2f(-1.442695041f * v));
}

__device__ __forceinline__ float fast_tanh(float v) {
    return 1.0f - 2.0f * __builtin_amdgcn_rcpf(1.0f + __builtin_amdgcn_exp2f(2.885390082f * v));
}

// 256 threads = 4 waves per batch element.
// lane l of wave w:  j = l>>4 (k-slice group), i = l&15, output m = w*16+i.
// Lane holds weights for ALL 4 gates of output m over k in [16j, 16j+16):
//   4 gates x 4 float4 = 64 floats, pinned in VGPRs.
// Per step: 4 broadcast ds_read_b128 (h slice) + 64 FMA, then an 8-shuffle
// butterfly all-reduce over the 4 j-groups; every lane then has all 4 gate
// sums and computes c,h redundantly (bit-identical); j==0 lanes write h.
__global__ __launch_bounds__(256)
__attribute__((amdgpu_waves_per_eu(2, 2)))
void bilstm_kernel(const float* __restrict__ x,
                   const float* __restrict__ w_ih_f,
                   const float* __restrict__ w_hh_f,
                   const float* __restrict__ b_ih_f,
                   const float* __restrict__ b_hh_f,
                   const float* __restrict__ w_ih_b,
                   const float* __restrict__ b_ih_b,
                   const float* __restrict__ b_hh_b,
                   const float* __restrict__ w_fc,
                   const float* __restrict__ b_fc,
                   float* __restrict__ out,
                   int T)
{
    const int b   = blockIdx.x;
    const int tid = threadIdx.x;
    const int w   = tid >> 6;        // wave 0..3
    const int l   = tid & 63;        // lane 0..63
    const int j   = l >> 4;          // k-slice group 0..3
    const int i   = l & 15;
    const int m   = (w << 4) | i;    // output index 0..63

    __shared__ float hbuf[2][HDIM];

    // ---- per-lane weights: 4 gates x k-slice [16j,16j+16) ----
    float4 wv[4][4];
    float  wx[4], bz[4];
    #pragma unroll
    for (int g = 0; g < 4; ++g) {
        const int r = (g << 6) | m;
        const float* row = w_hh_f + (size_t)r * HDIM + (j << 4);
        #pragma unroll
        for (int q = 0; q < 4; ++q) wv[g][q] = ((const float4*)row)[q];
        wx[g] = w_ih_f[(size_t)r * 4 + j];               // x-weight, component j
        bz[g] = (j == 0) ? (b_ih_f[r] + b_hh_f[r]) : 0.0f;  // bias seeded once
    }
    // Pin weights: forbid rematerialization inside the t-loop.
    #pragma unroll
    for (int g = 0; g < 4; ++g) {
        #pragma unroll
        for (int q = 0; q < 4; ++q)
            asm volatile("" : "+v"(wv[g][q].x), "+v"(wv[g][q].y),
                              "+v"(wv[g][q].z), "+v"(wv[g][q].w));
    }
    asm volatile("" : "+v"(wx[0]), "+v"(wx[1]), "+v"(wx[2]), "+v"(wx[3]));
    asm volatile("" : "+v"(bz[0]), "+v"(bz[1]), "+v"(bz[2]), "+v"(bz[3]));

    if (tid < HDIM) hbuf[0][tid] = 0.0f;
    __syncthreads();

    const float* xb = x + (size_t)b * T * 4;
    float4 xcur = *(const float4*)(xb);    // t = 0
    float c = 0.0f, h = 0.0f;
    int rb = 0;

    for (int t = 0; t < T; ++t) {
        const int tn = (t + 1 < T) ? t + 1 : T - 1;
        float4 xnext = *(const float4*)(xb + 4 * tn);

        // my x component
        const float xj = (j == 0) ? xcur.x : (j == 1) ? xcur.y
                       : (j == 2) ? xcur.z : xcur.w;

        // read my h slice: 4 broadcast float4 loads, issued together
        const float4* hp = (const float4*)(&hbuf[rb][j << 4]);
        float4 h0 = hp[0], h1 = hp[1], h2 = hp[2], h3 = hp[3];

        float p0 = bz[0] + wx[0] * xj;
        float p1 = bz[1] + wx[1] * xj;
        float p2 = bz[2] + wx[2] * xj;
        float p3 = bz[3] + wx[3] * xj;

        #define ACC(hq, q)                                             \
            p0 += wv[0][q].x * hq.x; p0 += wv[0][q].y * hq.y;          \
            p0 += wv[0][q].z * hq.z; p0 += wv[0][q].w * hq.w;          \
            p1 += wv[1][q].x * hq.x; p1 += wv[1][q].y * hq.y;          \
            p1 += wv[1][q].z * hq.z; p1 += wv[1][q].w * hq.w;          \
            p2 += wv[2][q].x * hq.x; p2 += wv[2][q].y * hq.y;          \
            p2 += wv[2][q].z * hq.z; p2 += wv[2][q].w * hq.w;          \
            p3 += wv[3][q].x * hq.x; p3 += wv[3][q].y * hq.y;          \
            p3 += wv[3][q].z * hq.z; p3 += wv[3][q].w * hq.w;
        ACC(h0, 0) ACC(h1, 1) ACC(h2, 2) ACC(h3, 3)
        #undef ACC

        // butterfly all-reduce across the 4 j-groups (lanes l, l^16, l^32, l^48)
        p0 += __shfl_xor(p0, 16);
        p1 += __shfl_xor(p1, 16);
        p2 += __shfl_xor(p2, 16);
        p3 += __shfl_xor(p3, 16);
        p0 += __shfl_xor(p0, 32);
        p1 += __shfl_xor(p1, 32);
        p2 += __shfl_xor(p2, 32);
        p3 += __shfl_xor(p3, 32);

        // all lanes compute the cell redundantly (bit-identical inputs)
        const float gi = fast_sigmoid(p0);
        const float gf = fast_sigmoid(p1);
        const float gg = fast_tanh(p2);
        const float go = fast_sigmoid(p3);
        c = gf * c + gi * gg;
        h = go * fast_tanh(c);

        if (l < 16) hbuf[rb ^ 1][m] = h;   // j==0 lanes write h[m]
        __syncthreads();
        rb ^= 1;
        xcur = xnext;
    }

    // ---- epilogue: wave 0 handles backward cell + fc + sigmoid ----
    if (w == 0) {
        // backward-direction single cell from zero state at x[:, T-1]
        float gb[4];
        #pragma unroll
        for (int jj = 0; jj < 4; ++jj) {
            const int rr2 = (jj << 6) | l;
            float4 wb = *(const float4*)(w_ih_b + (size_t)rr2 * 4);
            gb[jj] = b_ih_b[rr2] + b_hh_b[rr2]
                   + wb.x * xcur.x + wb.y * xcur.y + wb.z * xcur.z + wb.w * xcur.w;
        }
        const float ib  = fast_sigmoid(gb[0]);
        const float ggb = fast_tanh(gb[2]);
        const float ob  = fast_sigmoid(gb[3]);
        const float cb  = ib * ggb;
        const float hb  = ob * fast_tanh(cb);

        const float hf = hbuf[rb][l];
        float p = w_fc[l] * hf + w_fc[HDIM + l] * hb;
        #pragma unroll
        for (int off = 32; off; off >>= 1) p += __shfl_xor(p, off);

        if (l == 0) out[b] = fast_sigmoid(p + b_fc[0]);
    }
}

extern "C" void kernel_launch(void* const* d_in, const int* in_sizes, int n_in,
                              void* d_out, int out_size, void* d_ws, size_t ws_size,
                              hipStream_t stream) {
    const float* x      = (const float*)d_in[0];
    const float* w_ih_f = (const float*)d_in[1];
    const float* w_hh_f = (const float*)d_in[2];
    const float* b_ih_f = (const float*)d_in[3];
    const float* b_hh_f = (const float*)d_in[4];
    const float* w_ih_b = (const float*)d_in[5];
    // d_in[6] = w_hh_b — unused (backward cell starts from zero state)
    const float* b_ih_b = (const float*)d_in[7];
    const float* b_hh_b = (const float*)d_in[8];
    const float* w_fc   = (const float*)d_in[9];
    const float* b_fc   = (const float*)d_in[10];
    float* out = (float*)d_out;

    const int B = out_size;                 // 512
    const int T = in_sizes[0] / (B * 4);    // 1000

    bilstm_kernel<<<dim3(B), dim3(256), 0, stream>>>(
        x, w_ih_f, w_hh_f, b_ih_f, b_hh_f,
        w_ih_b, b_ih_b, b_hh_b, w_fc, b_fc, out, T);
}

// Round 6
// 503.307 us; speedup vs baseline: 1.4951x; 1.0643x over previous
//
#include <hip/hip_runtime.h>

#define HDIM 64

__device__ __forceinline__ float fast_sigmoid(float v) {
    return __builtin_amdgcn_rcpf(1.0f + __builtin_amdgcn_exp2f(-1.442695041f * v));
}

__device__ __forceinline__ float fast_tanh(float v) {
    return 1.0f - 2.0f * __builtin_amdgcn_rcpf(1.0f + __builtin_amdgcn_exp2f(2.885390082f * v));
}

// 256 threads = 4 waves per batch element.
// lane l of wave w:  j = l>>4 (k-slice group), i = l&15, output m = w*16+i.
// Lane holds weights for ALL 4 gates of output m over k in [16j,16j+16):
//   64 floats pinned in VGPRs.
// x is staged through LDS in 64-timestep chunks so the per-step loop has NO
// global loads (the compiler's vmcnt(0)-drain-before-barrier otherwise
// serializes an L2 latency into every step).
// T is assumed EVEN (T=1000) so the 2x-unrolled step loop keeps the h
// double-buffer parity static.
__global__ __launch_bounds__(256)
__attribute__((amdgpu_waves_per_eu(2, 2)))
void bilstm_kernel(const float* __restrict__ x,
                   const float* __restrict__ w_ih_f,
                   const float* __restrict__ w_hh_f,
                   const float* __restrict__ b_ih_f,
                   const float* __restrict__ b_hh_f,
                   const float* __restrict__ w_ih_b,
                   const float* __restrict__ b_ih_b,
                   const float* __restrict__ b_hh_b,
                   const float* __restrict__ w_fc,
                   const float* __restrict__ b_fc,
                   float* __restrict__ out,
                   int T)
{
    const int b   = blockIdx.x;
    const int tid = threadIdx.x;
    const int w   = tid >> 6;        // wave 0..3
    const int l   = tid & 63;        // lane 0..63
    const int j   = l >> 4;          // k-slice group 0..3
    const int i   = l & 15;
    const int m   = (w << 4) | i;    // output index 0..63

    __shared__ float hbuf[2][HDIM];
    __shared__ float xstage[2][256];   // 64 timesteps x 4 floats, double-buffered

    // ---- per-lane weights: 4 gates x k-slice [16j,16j+16) ----
    float4 wv[4][4];
    float  wx[4], bz[4];
    #pragma unroll
    for (int g = 0; g < 4; ++g) {
        const int r = (g << 6) | m;
        const float* row = w_hh_f + (size_t)r * HDIM + (j << 4);
        #pragma unroll
        for (int q = 0; q < 4; ++q) wv[g][q] = ((const float4*)row)[q];
        wx[g] = w_ih_f[(size_t)r * 4 + j];                  // x-weight, component j
        bz[g] = (j == 0) ? (b_ih_f[r] + b_hh_f[r]) : 0.0f;  // bias seeded once
    }
    // Pin weights: forbid rematerialization inside the t-loop.
    #pragma unroll
    for (int g = 0; g < 4; ++g) {
        #pragma unroll
        for (int q = 0; q < 4; ++q)
            asm volatile("" : "+v"(wv[g][q].x), "+v"(wv[g][q].y),
                              "+v"(wv[g][q].z), "+v"(wv[g][q].w));
    }
    asm volatile("" : "+v"(wx[0]), "+v"(wx[1]), "+v"(wx[2]), "+v"(wx[3]));
    asm volatile("" : "+v"(bz[0]), "+v"(bz[1]), "+v"(bz[2]), "+v"(bz[3]));

    const float* xb = x + (size_t)b * T * 4;
    const int lim = T * 4 - 1;

    // prologue: stage chunk 0, zero h
    {
        int idx = tid;  if (idx > lim) idx = lim;
        xstage[0][tid] = xb[idx];
    }
    if (tid < HDIM) hbuf[0][tid] = 0.0f;
    __syncthreads();

    float c = 0.0f, h = 0.0f;
    const int NCH = (T + 63) >> 6;   // chunks of 64 timesteps

    for (int ch = 0; ch < NCH; ++ch) {
        const int nst = ((T - (ch << 6)) < 64) ? (T - (ch << 6)) : 64;
        const float* xs = xstage[ch & 1];
        const bool more = (ch + 1 < NCH);
        float xnf = 0.0f;
        if (more) {
            int idx = ((ch + 1) << 8) + tid;  if (idx > lim) idx = lim;
            xnf = xb[idx];   // drained at first in-chunk barrier: exposed once / 64 steps
        }

        #define ACCP(HV, Q)                                               \
            p0 += wv[0][Q].x * HV.x; p0 += wv[0][Q].y * HV.y;             \
            p0 += wv[0][Q].z * HV.z; p0 += wv[0][Q].w * HV.w;             \
            p1 += wv[1][Q].x * HV.x; p1 += wv[1][Q].y * HV.y;             \
            p1 += wv[1][Q].z * HV.z; p1 += wv[1][Q].w * HV.w;             \
            p2 += wv[2][Q].x * HV.x; p2 += wv[2][Q].y * HV.y;             \
            p2 += wv[2][Q].z * HV.z; p2 += wv[2][Q].w * HV.w;             \
            p3 += wv[3][Q].x * HV.x; p3 += wv[3][Q].y * HV.y;             \
            p3 += wv[3][Q].z * HV.z; p3 += wv[3][Q].w * HV.w;
        #define ACCQ(HV, Q)                                               \
            q0 += wv[0][Q].x * HV.x; q0 += wv[0][Q].y * HV.y;             \
            q0 += wv[0][Q].z * HV.z; q0 += wv[0][Q].w * HV.w;             \
            q1 += wv[1][Q].x * HV.x; q1 += wv[1][Q].y * HV.y;             \
            q1 += wv[1][Q].z * HV.z; q1 += wv[1][Q].w * HV.w;             \
            q2 += wv[2][Q].x * HV.x; q2 += wv[2][Q].y * HV.y;             \
            q2 += wv[2][Q].z * HV.z; q2 += wv[2][Q].w * HV.w;             \
            q3 += wv[3][Q].x * HV.x; q3 += wv[3][Q].y * HV.y;             \
            q3 += wv[3][Q].z * HV.z; q3 += wv[3][Q].w * HV.w;

        #define STEP(S, RA, RB) do {                                       \
            const float xj = xs[((S) << 2) + j];                           \
            const float4* hp = (const float4*)(&hbuf[RA][j << 4]);         \
            float4 h0 = hp[0], h1 = hp[1], h2 = hp[2], h3 = hp[3];         \
            float p0 = bz[0] + wx[0] * xj, p1 = bz[1] + wx[1] * xj;        \
            float p2 = bz[2] + wx[2] * xj, p3 = bz[3] + wx[3] * xj;        \
            float q0 = 0.0f, q1 = 0.0f, q2 = 0.0f, q3 = 0.0f;              \
            ACCP(h0, 0) ACCQ(h1, 1) ACCP(h2, 2) ACCQ(h3, 3)                \
            p0 += q0; p1 += q1; p2 += q2; p3 += q3;                        \
            p0 += __shfl_xor(p0, 16); p1 += __shfl_xor(p1, 16);            \
            p2 += __shfl_xor(p2, 16); p3 += __shfl_xor(p3, 16);            \
            p0 += __shfl_xor(p0, 32); p1 += __shfl_xor(p1, 32);            \
            p2 += __shfl_xor(p2, 32); p3 += __shfl_xor(p3, 32);            \
            const float gi = fast_sigmoid(p0);                             \
            const float gf = fast_sigmoid(p1);                             \
            const float gg = fast_tanh(p2);                                \
            const float go = fast_sigmoid(p3);                             \
            c = gf * c + gi * gg;                                          \
            h = go * fast_tanh(c);                                         \
            if (l < 16) hbuf[RB][m] = h;                                   \
            __syncthreads();                                               \
        } while (0)

        for (int s = 0; s < nst; s += 2) {
            STEP(s,     0, 1);
            STEP(s + 1, 1, 0);
        }
        #undef STEP
        #undef ACCP
        #undef ACCQ

        if (more) {
            xstage[(ch + 1) & 1][tid] = xnf;
            __syncthreads();
        }
    }

    // ---- epilogue: wave 0 handles backward cell + fc + sigmoid ----
    if (w == 0) {
        // backward-direction single cell from zero state at x[:, T-1]
        // (w_hh_b never multiplies nonzero state)
        float4 xl = *(const float4*)(xb + 4 * (T - 1));
        float gb[4];
        #pragma unroll
        for (int jj = 0; jj < 4; ++jj) {
            const int rr2 = (jj << 6) | l;
            float4 wb = *(const float4*)(w_ih_b + (size_t)rr2 * 4);
            gb[jj] = b_ih_b[rr2] + b_hh_b[rr2]
                   + wb.x * xl.x + wb.y * xl.y + wb.z * xl.z + wb.w * xl.w;
        }
        const float ib  = fast_sigmoid(gb[0]);
        const float ggb = fast_tanh(gb[2]);
        const float ob  = fast_sigmoid(gb[3]);
        const float cb  = ib * ggb;
        const float hb  = ob * fast_tanh(cb);

        const float hf = hbuf[0][l];   // T even -> final h lands in buffer 0
        float p = w_fc[l] * hf + w_fc[HDIM + l] * hb;
        #pragma unroll
        for (int off = 32; off; off >>= 1) p += __shfl_xor(p, off);

        if (l == 0) out[b] = fast_sigmoid(p + b_fc[0]);
    }
}

extern "C" void kernel_launch(void* const* d_in, const int* in_sizes, int n_in,
                              void* d_out, int out_size, void* d_ws, size_t ws_size,
                              hipStream_t stream) {
    const float* x      = (const float*)d_in[0];
    const float* w_ih_f = (const float*)d_in[1];
    const float* w_hh_f = (const float*)d_in[2];
    const float* b_ih_f = (const float*)d_in[3];
    const float* b_hh_f = (const float*)d_in[4];
    const float* w_ih_b = (const float*)d_in[5];
    // d_in[6] = w_hh_b — unused (backward cell starts from zero state)
    const float* b_ih_b = (const float*)d_in[7];
    const float* b_hh_b = (const float*)d_in[8];
    const float* w_fc   = (const float*)d_in[9];
    const float* b_fc   = (const float*)d_in[10];
    float* out = (float*)d_out;

    const int B = out_size;                 // 512
    const int T = in_sizes[0] / (B * 4);    // 1000

    bilstm_kernel<<<dim3(B), dim3(256), 0, stream>>>(
        x, w_ih_f, w_hh_f, b_ih_f, b_hh_f,
        w_ih_b, b_ih_b, b_hh_b, w_fc, b_fc, out, T);
}